// Round 1
// baseline (239.250 us; speedup 1.0000x reference)
//
#include <hip/hip_runtime.h>

#define OUT_HW   14
#define NSAMP    28      // OUT_HW * RATIO
#define NBINS    196     // 14*14
#define C_TOTAL  256
#define C_PER_BLK 64
#define NBOXES   512

struct __align__(16) AxisEntry { int lo, hi; float wlo, whi; };

__global__ __launch_bounds__(256) void roi_pool_kernel(
    const float* __restrict__ x0, const float* __restrict__ x1,
    const float* __restrict__ x2, const float* __restrict__ x3,
    const float* __restrict__ boxes, float* __restrict__ out)
{
    __shared__ __align__(16) AxisEntry sy[NSAMP];
    __shared__ __align__(16) AxisEntry sx[NSAMP];

    const int m    = blockIdx.x;       // box index
    const int cblk = blockIdx.y;       // channel chunk

    // ---- per-box (block-uniform) setup ----
    const float b0  = boxes[m * 5 + 0];
    const float bx0 = boxes[m * 5 + 1];
    const float by0 = boxes[m * 5 + 2];
    const float bx1 = boxes[m * 5 + 3];
    const float by1 = boxes[m * 5 + 4];

    // level assignment: floor(4 + log2(sqrt(w*h)/224 + 1e-8)), clip [2,5], -2
    const float szw = bx1 - bx0;
    const float szh = by1 - by0;
    const float sz  = sqrtf(szw * szh);
    int lvl = (int)floorf(4.0f + log2f(sz * (1.0f / 224.0f) + 1e-8f));
    lvl = min(max(lvl, 2), 5) - 2;

    const float scales[4] = {0.25f, 0.125f, 0.0625f, 0.03125f};
    const int   dims[4]   = {256, 128, 64, 32};
    const float scale = scales[lvl];
    const int   H = dims[lvl];
    const int   W = dims[lvl];
    const float* feat = (lvl == 0) ? x0 : (lvl == 1) ? x1 : (lvl == 2) ? x2 : x3;
    const int bidx = (int)b0;

    // aligned=True ROI coords on this level
    const float rx0 = bx0 * scale - 0.5f;
    const float ry0 = by0 * scale - 0.5f;
    const float rx1 = bx1 * scale - 0.5f;
    const float ry1 = by1 * scale - 0.5f;
    const float binw = (rx1 - rx0) * (1.0f / (float)OUT_HW);
    const float binh = (ry1 - ry0) * (1.0f / (float)OUT_HW);

    const int tid = threadIdx.x;

    // ---- per-box axis metadata into LDS (56 entries) ----
    if (tid < 2 * NSAMP) {
        const int  s   = (tid >= NSAMP) ? (tid - NSAMP) : tid;
        const bool isx = (tid >= NSAMP);
        // sample fractional position within ROI: bin + (sub + 0.5)/ratio
        const float frac  = (float)(s >> 1) + 0.25f + 0.5f * (float)(s & 1);
        const float coord = isx ? (rx0 + frac * binw) : (ry0 + frac * binh);
        const float L     = (float)(isx ? W : H);

        const bool  valid = (coord >= -1.0f) && (coord <= L);
        const float cc    = fminf(fmaxf(coord, 0.0f), L - 1.0f);
        const float lo    = floorf(cc);
        const float hi    = fminf(lo + 1.0f, L - 1.0f);
        float whi = cc - lo;
        float wlo = 1.0f - whi;
        if (!valid) { wlo = 0.0f; whi = 0.0f; }

        AxisEntry e;
        e.lo = (int)lo; e.hi = (int)hi; e.wlo = wlo; e.whi = whi;
        if (isx) sx[s] = e; else sy[s] = e;
    }
    __syncthreads();

    // ---- main loop: 64 channels x 196 bins, coalesced writes ----
    const int HW = H * W;
    const float* fb = feat + (size_t)(bidx * C_TOTAL + cblk * C_PER_BLK) * HW;
    float* ob = out + ((size_t)m * C_TOTAL + (size_t)cblk * C_PER_BLK) * NBINS;

    for (int e = tid; e < C_PER_BLK * NBINS; e += 256) {
        const int c  = e / NBINS;
        const int r  = e - c * NBINS;
        const int ph = r / OUT_HW;
        const int pw = r - ph * OUT_HW;

        const float* f = fb + (size_t)c * HW;

        float acc = 0.0f;
        #pragma unroll
        for (int i = 0; i < 2; ++i) {
            const AxisEntry ey = sy[2 * ph + i];
            const float* frl = f + ey.lo * W;
            const float* frh = f + ey.hi * W;
            #pragma unroll
            for (int j = 0; j < 2; ++j) {
                const AxisEntry ex = sx[2 * pw + j];
                const float vlo = ex.wlo * frl[ex.lo] + ex.whi * frl[ex.hi];
                const float vhi = ex.wlo * frh[ex.lo] + ex.whi * frh[ex.hi];
                acc += ey.wlo * vlo + ey.whi * vhi;
            }
        }
        ob[e] = acc * 0.25f;   // mean over the 2x2 samples
    }
}

extern "C" void kernel_launch(void* const* d_in, const int* in_sizes, int n_in,
                              void* d_out, int out_size, void* d_ws, size_t ws_size,
                              hipStream_t stream) {
    const float* x0    = (const float*)d_in[0];
    const float* x1    = (const float*)d_in[1];
    const float* x2    = (const float*)d_in[2];
    const float* x3    = (const float*)d_in[3];
    const float* boxes = (const float*)d_in[4];
    float* out = (float*)d_out;

    dim3 grid(NBOXES, C_TOTAL / C_PER_BLK);
    dim3 block(256);
    roi_pool_kernel<<<grid, block, 0, stream>>>(x0, x1, x2, x3, boxes, out);
}